// Round 8
// baseline (326.623 us; speedup 1.0000x reference)
//
#include <hip/hip_runtime.h>

typedef unsigned short u16;
typedef unsigned int u32;

#define BATCH 4
#define NTOK 4096
#define SCALE_ATTN 0.125f

typedef float f32x4 __attribute__((ext_vector_type(4)));
typedef __bf16 bf16x8 __attribute__((ext_vector_type(8)));

__device__ __forceinline__ float b2f(u16 s) { return __uint_as_float(((u32)s) << 16); }
__device__ __forceinline__ u16 f2bf(float f) {
    u32 u = __float_as_uint(f);
    u += 0x7FFFu + ((u >> 16) & 1u);
    return (u16)(u >> 16);
}
__device__ __forceinline__ u32 pk2(float x, float y) {
    return (u32)f2bf(x) | ((u32)f2bf(y) << 16);
}
// truncating pack (attention probabilities only)
__device__ __forceinline__ u32 pk2t(float x, float y) {
    return (__float_as_uint(x) >> 16) | (__float_as_uint(y) & 0xFFFF0000u);
}
__device__ __forceinline__ uint4 pack8(float4 a, float4 b) {
    uint4 r;
    r.x = pk2(a.x, a.y); r.y = pk2(a.z, a.w);
    r.z = pk2(b.x, b.y); r.w = pk2(b.z, b.w);
    return r;
}
__device__ __forceinline__ f32x4 mfma16(uint4 a, uint4 b, f32x4 c) {
    return __builtin_amdgcn_mfma_f32_16x16x32_bf16(
        __builtin_bit_cast(bf16x8, a), __builtin_bit_cast(bf16x8, b), c, 0, 0, 0);
}

// ---------------------------------------------------------------------------
// One-shot f32 -> bf16 conversion of all weights + tgt + memory.
// ---------------------------------------------------------------------------
struct CvtTable {
    const float* src[10];
    u32 start[10];
};
__global__ __launch_bounds__(256) void cvt_bf16_kernel(CvtTable tab, u16* __restrict__ dst)
{
    u32 i8 = (blockIdx.x * 256u + threadIdx.x) * 8u;
    int t = 0;
    #pragma unroll
    for (int k = 1; k < 10; ++k) t += (i8 >= tab.start[k]) ? 1 : 0;
    const float* s = tab.src[t] + (i8 - tab.start[t]);
    float4 f0 = *(const float4*)s;
    float4 f1 = *(const float4*)(s + 4);
    *(uint4*)(dst + i8) = pack8(f0, f1);
}

// ---------------------------------------------------------------------------
// GEMM: C[M,N](bf16) = A[M,K](bf16) @ B[N,K]^T(bf16) + bias(f32), opt ReLU.
// 64x64 tile everywhere (occupancy-first: grids 512..2048 blocks, 2-8/CU).
// global_load_lds(16B) staging, fragment-major LDS, double-buffered K-loop.
// Dual bias pointers (cols >= split use bias2) for fused concat GEMMs.
// ---------------------------------------------------------------------------
template<int BM, int BN>
__global__ __launch_bounds__(256) void gemm_lds_kernel(
    const u16* __restrict__ A, const u16* __restrict__ B,
    const float* __restrict__ bias, const float* __restrict__ bias2, int split,
    u16* __restrict__ C, int M, int N, int K, int relu)
{
    constexpr int WMF = BM / 32;
    constexpr int WNF = BN / 32;
    constexpr int AIW = BM / 32;
    constexpr int BIW = BN / 32;

    __shared__ u16 As[2][BM * 64];
    __shared__ u16 Bs[2][BN * 64];

    const int tid = threadIdx.x;
    const int wave = tid >> 6, lane = tid & 63;
    const int lm = lane & 15, quad = lane >> 4;
    const int m0 = blockIdx.y * BM, n0 = blockIdx.x * BN;
    const int wr = wave >> 1, wc = wave & 1;
    const int lk = (lane >> 4) * 8;

    f32x4 acc[WMF][WNF] = {};

    auto stage = [&](int buf, int k0) {
        #pragma unroll
        for (int t = 0; t < AIW; ++t) {
            int j = wave * AIW + t;
            int i = j >> 1, c = j & 1;
            const u16* gp = A + (size_t)(m0 + i * 16 + lm) * K + k0 + c * 32 + lk;
            __builtin_amdgcn_global_load_lds(
                (const __attribute__((address_space(1))) u32*)gp,
                (__attribute__((address_space(3))) u32*)(&As[buf][j * 512]), 16, 0, 0);
        }
        #pragma unroll
        for (int t = 0; t < BIW; ++t) {
            int j = wave * BIW + t;
            int i = j >> 1, c = j & 1;
            const u16* gp = B + (size_t)(n0 + i * 16 + lm) * K + k0 + c * 32 + lk;
            __builtin_amdgcn_global_load_lds(
                (const __attribute__((address_space(1))) u32*)gp,
                (__attribute__((address_space(3))) u32*)(&Bs[buf][j * 512]), 16, 0, 0);
        }
    };

    stage(0, 0);
    int cur = 0;
    for (int k0 = 0; k0 < K; k0 += 64) {
        __syncthreads();                    // drains loads of buf `cur`
        if (k0 + 64 < K) stage(cur ^ 1, k0 + 64);   // overlap with compute
        #pragma unroll
        for (int kk = 0; kk < 2; ++kk) {
            uint4 af[WMF], bf[WNF];
            #pragma unroll
            for (int i2 = 0; i2 < WMF; ++i2) {
                int g = wr * WMF + i2;
                af[i2] = *(const uint4*)(&As[cur][((g * 8 + kk * 4 + quad) * 16 + lm) * 8]);
            }
            #pragma unroll
            for (int j2 = 0; j2 < WNF; ++j2) {
                int g = wc * WNF + j2;
                bf[j2] = *(const uint4*)(&Bs[cur][((g * 8 + kk * 4 + quad) * 16 + lm) * 8]);
            }
            #pragma unroll
            for (int i2 = 0; i2 < WMF; ++i2)
                #pragma unroll
                for (int j2 = 0; j2 < WNF; ++j2)
                    acc[i2][j2] = mfma16(af[i2], bf[j2], acc[i2][j2]);
        }
        cur ^= 1;
    }

    #pragma unroll
    for (int j2 = 0; j2 < WNF; ++j2) {
        int cg = n0 + (wc * WNF + j2) * 16 + lm;
        float bv = (cg < split) ? bias[cg] : bias2[cg - split];
        #pragma unroll
        for (int i2 = 0; i2 < WMF; ++i2) {
            #pragma unroll
            for (int r = 0; r < 4; ++r) {
                int rg = m0 + (wr * WMF + i2) * 16 + quad * 4 + r;
                float v = acc[i2][j2][r] + bv;
                if (relu) v = fmaxf(v, 0.f);
                C[(size_t)rg * N + cg] = f2bf(v);
            }
        }
    }
}

// ---------------------------------------------------------------------------
// Fused residual add + LayerNorm over D=512.
// ---------------------------------------------------------------------------
__global__ __launch_bounds__(256) void add_ln_kernel(
    const u16* __restrict__ a, const void* __restrict__ r,
    const float* __restrict__ g, const float* __restrict__ be,
    void* __restrict__ out, int r_f32, int out_f32)
{
    const int row = blockIdx.x, tid = threadIdx.x;
    u32 av = *(const u32*)(a + (size_t)row * 512 + tid * 2);
    float r0, r1;
    if (r_f32) {
        float2 rv = *(const float2*)((const float*)r + (size_t)row * 512 + tid * 2);
        r0 = rv.x; r1 = rv.y;
    } else {
        u32 rv = *(const u32*)((const u16*)r + (size_t)row * 512 + tid * 2);
        r0 = b2f((u16)(rv & 0xFFFFu)); r1 = b2f((u16)(rv >> 16));
    }
    float v0 = b2f((u16)(av & 0xFFFFu)) + r0;
    float v1 = b2f((u16)(av >> 16)) + r1;
    float s = v0 + v1, q = v0 * v0 + v1 * v1;
    #pragma unroll
    for (int m = 1; m < 64; m <<= 1) { s += __shfl_xor(s, m); q += __shfl_xor(q, m); }
    __shared__ float ss[4], qq[4];
    int wave = tid >> 6, lane = tid & 63;
    if (lane == 0) { ss[wave] = s; qq[wave] = q; }
    __syncthreads();
    s = ss[0] + ss[1] + ss[2] + ss[3];
    q = qq[0] + qq[1] + qq[2] + qq[3];
    float mean = s * (1.f / 512.f);
    float var = q * (1.f / 512.f) - mean * mean;
    float rstd = rsqrtf(var + 1e-5f);
    float2 gv = *(const float2*)(g + tid * 2);
    float2 bv = *(const float2*)(be + tid * 2);
    float o0 = (v0 - mean) * rstd * gv.x + bv.x;
    float o1 = (v1 - mean) * rstd * gv.y + bv.y;
    if (out_f32) {
        float2 ov; ov.x = o0; ov.y = o1;
        *(float2*)((float*)out + (size_t)row * 512 + tid * 2) = ov;
    } else {
        *(u32*)((u16*)out + (size_t)row * 512 + tid * 2) = pk2(o0, o1);
    }
}

// ---------------------------------------------------------------------------
// Self-attention, full MFMA flash kernel.
// Round 8: 128-key chunks (8 iterations, half the barriers of round 5's 16).
// ---------------------------------------------------------------------------
__global__ __launch_bounds__(256) void self_attn_kernel(
    const u16* __restrict__ qkv, u16* __restrict__ o)
{
    const int qb = blockIdx.x;          // 0..15 (64 q-rows per block)
    const int bh = blockIdx.y;          // 0..31
    const int b = bh >> 3, h = bh & 7;
    const int tid = threadIdx.x;
    const int lane = tid & 63, wave = tid >> 6;
    const int lm = lane & 15, quad = lane >> 4;

    __shared__ u16 Ks[16 * 512];        // fragment-major, 128 keys (16 KB)
    __shared__ u16 Vt[64][136];         // [hd][key 0..127], +8 pad (17 KB)

    const int qrow0 = qb * 64 + wave * 16;
    const u16* qp = qkv + ((size_t)(qrow0 + lm) * BATCH + b) * 1536 + h * 64;
    uint4 qf0 = *(const uint4*)(qp + quad * 8);
    uint4 qf1 = *(const uint4*)(qp + 32 + quad * 8);

    f32x4 o4[4] = {};
    float m_s = -1e30f, l_s = 0.f;

    for (int c0 = 0; c0 < 1024; c0 += 128) {
        // --- K staging: 16 global_load_lds(16B), 4 per wave ---
        #pragma unroll
        for (int t2 = 0; t2 < 4; ++t2) {
            int j = wave * 4 + t2;            // 0..15
            int g = j >> 1, c = j & 1;
            const u16* gp = qkv + ((size_t)(c0 + g * 16 + lm) * BATCH + b) * 1536
                            + 512 + h * 64 + c * 32 + quad * 8;
            __builtin_amdgcn_global_load_lds(
                (const __attribute__((address_space(1))) u32*)gp,
                (__attribute__((address_space(3))) u32*)(Ks + j * 512), 16, 0, 0);
        }
        // --- V staging transposed: 128 keys x 64 hd, 4 iters ---
        #pragma unroll
        for (int i = 0; i < 4; ++i) {
            int c = tid + i * 256;            // 0..1023
            int key = c & 127, dv = (c >> 7) * 8;
            uint4 u = *(const uint4*)(
                qkv + ((size_t)(c0 + key) * BATCH + b) * 1536 + 1024 + h * 64 + dv);
            Vt[dv + 0][key] = (u16)(u.x & 0xFFFFu);
            Vt[dv + 1][key] = (u16)(u.x >> 16);
            Vt[dv + 2][key] = (u16)(u.y & 0xFFFFu);
            Vt[dv + 3][key] = (u16)(u.y >> 16);
            Vt[dv + 4][key] = (u16)(u.z & 0xFFFFu);
            Vt[dv + 5][key] = (u16)(u.z >> 16);
            Vt[dv + 6][key] = (u16)(u.w & 0xFFFFu);
            Vt[dv + 7][key] = (u16)(u.w >> 16);
        }
        __syncthreads();

        // --- S^T = K*Q^T over 128 keys ---
        f32x4 s[8] = {};
        #pragma unroll
        for (int t = 0; t < 8; ++t) {
            uint4 k0 = *(const uint4*)(Ks + t * 1024 + quad * 128 + lm * 8);
            uint4 k1 = *(const uint4*)(Ks + t * 1024 + 512 + quad * 128 + lm * 8);
            s[t] = mfma16(k0, qf0, s[t]);
            s[t] = mfma16(k1, qf1, s[t]);
        }

        // --- online softmax ---
        float mx = -1e30f;
        #pragma unroll
        for (int t = 0; t < 8; ++t)
            #pragma unroll
            for (int r = 0; r < 4; ++r) {
                s[t][r] *= SCALE_ATTN;
                mx = fmaxf(mx, s[t][r]);
            }
        mx = fmaxf(mx, __shfl_xor(mx, 16));
        mx = fmaxf(mx, __shfl_xor(mx, 32));
        float mn = fmaxf(m_s, mx);
        float alpha = __expf(m_s - mn);
        m_s = mn;
        float ps = 0.f;
        u32 pkx[8], pky[8];
        #pragma unroll
        for (int t = 0; t < 8; ++t) {
            float p0 = __expf(s[t][0] - mn);
            float p1 = __expf(s[t][1] - mn);
            float p2 = __expf(s[t][2] - mn);
            float p3 = __expf(s[t][3] - mn);
            ps += (p0 + p1) + (p2 + p3);
            pkx[t] = pk2t(p0, p1);
            pky[t] = pk2t(p2, p3);
        }
        ps += __shfl_xor(ps, 16);
        ps += __shfl_xor(ps, 32);
        l_s = l_s * alpha + ps;
        float av[4];
        #pragma unroll
        for (int r = 0; r < 4; ++r) av[r] = __shfl(alpha, quad * 20 + r);
        #pragma unroll
        for (int t = 0; t < 4; ++t)
            #pragma unroll
            for (int r = 0; r < 4; ++r) o4[t][r] *= av[r];

        // --- PV over 128 keys: 4 P-frags via shuffles ---
        #pragma unroll
        for (int kh = 0; kh < 4; ++kh) {
            int src1 = lm + 32 * (quad & 1);
            int src2 = src1 + 16;
            u32 xA = (u32)__shfl((int)pkx[2 * kh], src1);
            u32 xB = (u32)__shfl((int)pkx[2 * kh + 1], src1);
            u32 yA = (u32)__shfl((int)pky[2 * kh], src1);
            u32 yB = (u32)__shfl((int)pky[2 * kh + 1], src1);
            u32 zA = (u32)__shfl((int)pkx[2 * kh], src2);
            u32 zB = (u32)__shfl((int)pkx[2 * kh + 1], src2);
            u32 wA = (u32)__shfl((int)pky[2 * kh], src2);
            u32 wB = (u32)__shfl((int)pky[2 * kh + 1], src2);
            bool hiq = quad >= 2;
            uint4 pf;
            pf.x = hiq ? xB : xA;
            pf.y = hiq ? yB : yA;
            pf.z = hiq ? zB : zA;
            pf.w = hiq ? wB : wA;
            #pragma unroll
            for (int t = 0; t < 4; ++t) {
                uint4 vf = *(const uint4*)(&Vt[t * 16 + lm][kh * 32 + quad * 8]);
                o4[t] = mfma16(pf, vf, o4[t]);
            }
        }
        __syncthreads();
    }

    float linv = 1.f / l_s;
    float lv[4];
    #pragma unroll
    for (int r = 0; r < 4; ++r) lv[r] = __shfl(linv, quad * 20 + r);
    #pragma unroll
    for (int t = 0; t < 4; ++t) {
        #pragma unroll
        for (int r = 0; r < 4; ++r) {
            int row = qrow0 + quad * 4 + r;
            o[((size_t)row * BATCH + b) * 512 + h * 64 + t * 16 + lm] =
                f2bf(o4[t][r] * lv[r]);
        }
    }
}

// ---------------------------------------------------------------------------
// Sliding-window cross attention, MFMA band kernel (fused kv input).
// ---------------------------------------------------------------------------
__global__ __launch_bounds__(256) void sw_attn_kernel(
    const u16* __restrict__ q2, const u16* __restrict__ kv, u16* __restrict__ o)
{
    const int qb = blockIdx.x;          // 0..15
    const int bh = blockIdx.y;          // 0..31
    const int b = bh >> 3, h = bh & 7;
    const int tid = threadIdx.x;
    const int lane = tid & 63, wave = tid >> 6;
    const int lm = lane & 15, quad = lane >> 4;

    __shared__ u16 Ks[14 * 512];
    __shared__ u16 Vt[64][120];

    const int kbase = qb * 64 - 16;
    const int qrow0 = qb * 64 + wave * 16;

    const u16* qp = q2 + ((size_t)(qrow0 + lm) * BATCH + b) * 512 + h * 64;
    uint4 qf0 = *(const uint4*)(qp + quad * 8);
    uint4 qf1 = *(const uint4*)(qp + 32 + quad * 8);

    #pragma unroll
    for (int t2 = 0; t2 < 4; ++t2) {
        int j = wave * 4 + t2;
        if (j < 14) {
            int g = j >> 1, c = j & 1;
            int key = kbase + g * 16 + lm;
            key = min(max(key, 0), 1023);
            const u16* gp = kv + ((size_t)key * BATCH + b) * 1024 + h * 64
                            + c * 32 + quad * 8;
            __builtin_amdgcn_global_load_lds(
                (const __attribute__((address_space(1))) u32*)gp,
                (__attribute__((address_space(3))) u32*)(Ks + j * 512), 16, 0, 0);
        }
    }
    #pragma unroll
    for (int i = 0; i < 4; ++i) {
        int c = tid + i * 256;
        if (c < 896) {
            int key = c >> 3, dv = (c & 7) * 8;
            int j = kbase + key;
            j = min(max(j, 0), 1023);
            uint4 u = *(const uint4*)(kv + ((size_t)j * BATCH + b) * 1024 + 512 + h * 64 + dv);
            Vt[dv + 0][key] = (u16)(u.x & 0xFFFFu);
            Vt[dv + 1][key] = (u16)(u.x >> 16);
            Vt[dv + 2][key] = (u16)(u.y & 0xFFFFu);
            Vt[dv + 3][key] = (u16)(u.y >> 16);
            Vt[dv + 4][key] = (u16)(u.z & 0xFFFFu);
            Vt[dv + 5][key] = (u16)(u.z >> 16);
            Vt[dv + 6][key] = (u16)(u.w & 0xFFFFu);
            Vt[dv + 7][key] = (u16)(u.w >> 16);
        }
    }
    __syncthreads();

    f32x4 s[4] = {};
    #pragma unroll
    for (int t = 0; t < 4; ++t) {
        int tw = wave + t;
        uint4 k0 = *(const uint4*)(Ks + (tw * 2 + 0) * 512 + quad * 128 + lm * 8);
        uint4 k1 = *(const uint4*)(Ks + (tw * 2 + 1) * 512 + quad * 128 + lm * 8);
        s[t] = mfma16(k0, qf0, s[t]);
        s[t] = mfma16(k1, qf1, s[t]);
    }

    float mx = -1e30f;
    #pragma unroll
    for (int t = 0; t < 4; ++t) {
        #pragma unroll
        for (int r = 0; r < 4; ++r) {
            int kl = t * 16 + quad * 4 + r;
            int jj = qrow0 - 16 + kl;
            int d = kl - lm;
            bool valid = (d >= 0) && (d <= 32) && (jj >= 0) && (jj < 1024);
            s[t][r] = valid ? s[t][r] * SCALE_ATTN : -1e30f;
            mx = fmaxf(mx, s[t][r]);
        }
    }
    mx = fmaxf(mx, __shfl_xor(mx, 16));
    mx = fmaxf(mx, __shfl_xor(mx, 32));
    float ps = 0.f;
    u32 pkx[4], pky[4];
    #pragma unroll
    for (int t = 0; t < 4; ++t) {
        float p0 = __expf(s[t][0] - mx);
        float p1 = __expf(s[t][1] - mx);
        float p2 = __expf(s[t][2] - mx);
        float p3 = __expf(s[t][3] - mx);
        ps += (p0 + p1) + (p2 + p3);
        pkx[t] = pk2t(p0, p1);
        pky[t] = pk2t(p2, p3);
    }
    ps += __shfl_xor(ps, 16);
    ps += __shfl_xor(ps, 32);

    f32x4 o4[4] = {};
    #pragma unroll
    for (int kh = 0; kh < 2; ++kh) {
        int src1 = lm + 32 * (quad & 1);
        int src2 = src1 + 16;
        u32 xA = (u32)__shfl((int)pkx[2 * kh], src1);
        u32 xB = (u32)__shfl((int)pkx[2 * kh + 1], src1);
        u32 yA = (u32)__shfl((int)pky[2 * kh], src1);
        u32 yB = (u32)__shfl((int)pky[2 * kh + 1], src1);
        u32 zA = (u32)__shfl((int)pkx[2 * kh], src2);
        u32 zB = (u32)__shfl((int)pkx[2 * kh + 1], src2);
        u32 wA = (u32)__shfl((int)pky[2 * kh], src2);
        u32 wB = (u32)__shfl((int)pky[2 * kh + 1], src2);
        bool hiq = quad >= 2;
        uint4 pf;
        pf.x = hiq ? xB : xA;
        pf.y = hiq ? yB : yA;
        pf.z = hiq ? zB : zA;
        pf.w = hiq ? wB : wA;
        #pragma unroll
        for (int t = 0; t < 4; ++t) {
            uint4 vf = *(const uint4*)(&Vt[t * 16 + lm][wave * 16 + kh * 32 + quad * 8]);
            o4[t] = mfma16(pf, vf, o4[t]);
        }
    }

    float linv = 1.f / ps;
    float lv[4];
    #pragma unroll
    for (int r = 0; r < 4; ++r) lv[r] = __shfl(linv, quad * 20 + r);
    #pragma unroll
    for (int t = 0; t < 4; ++t) {
        #pragma unroll
        for (int r = 0; r < 4; ++r) {
            int row = qrow0 + quad * 4 + r;
            o[((size_t)row * BATCH + b) * 512 + h * 64 + t * 16 + lm] =
                f2bf(o4[t][r] * lv[r]);
        }
    }
}

// ---------------------------------------------------------------------------
// Host orchestration
// ---------------------------------------------------------------------------
static inline void gemm64(hipStream_t st, const u16* A, const u16* B,
                          const float* bias, const float* bias2, int split,
                          u16* C, int M, int N, int K, int relu)
{
    dim3 g(N / 64, M / 64);
    gemm_lds_kernel<64, 64><<<g, dim3(256), 0, st>>>(A, B, bias, bias2, split,
                                                     C, M, N, K, relu);
}

extern "C" void kernel_launch(void* const* d_in, const int* in_sizes, int n_in,
                              void* d_out, int out_size, void* d_ws, size_t ws_size,
                              hipStream_t stream)
{
    const float* tgt        = (const float*)d_in[0];
    const float* memory     = (const float*)d_in[1];
    const float* in_proj_w  = (const float*)d_in[2];
    const float* in_proj_b  = (const float*)d_in[3];
    const float* out_proj_w = (const float*)d_in[4];
    const float* out_proj_b = (const float*)d_in[5];
    const float* sw_q_w = (const float*)d_in[6];
    const float* sw_q_b = (const float*)d_in[7];
    const float* sw_k_w = (const float*)d_in[8];
    const float* sw_k_b = (const float*)d_in[9];
    const float* sw_v_w = (const float*)d_in[10];
    const float* sw_v_b = (const float*)d_in[11];
    const float* sw_o_w = (const float*)d_in[12];
    const float* sw_o_b = (const float*)d_in[13];
    const float* lin1_w = (const float*)d_in[14];
    const float* lin1_b = (const float*)d_in[15];
    const float* lin2_w = (const float*)d_in[16];
    const float* lin2_b = (const float*)d_in[17];
    const float* n1_g = (const float*)d_in[18];
    const float* n1_b = (const float*)d_in[19];
    const float* n2_g = (const float*)d_in[20];
    const float* n2_b = (const float*)d_in[21];
    const float* n3_g = (const float*)d_in[22];
    const float* n3_b = (const float*)d_in[23];

    u16* ws = (u16*)d_ws;
    u16* qkv  = ws;                    // 6291456
    u16* x1   = ws + 6291456;          // 2097152
    u16* bufA = ws + 8388608;          // 2097152
    u16* bufB = ws + 10485760;         // 2097152
    u16* x2   = ws + 12582912;         // 2097152
    u16* q2 = qkv;                     // 2097152 (reuse qkv region)
    u16* kv = qkv + 2097152;           // 4194304 = [4096][1024] fused k|v
    u16* hbuf = qkv;                   // spans qkv+x1 (both dead by FFN)

    u16* wc = ws + 14680064;
    u16* tgtb  = wc;
    u16* memb  = wc + 2097152;
    u16* inpb  = wc + 4194304;
    u16* outpb = wc + 4980736;
    u16* swqb  = wc + 5242880;
    u16* swkb  = wc + 5505024;         // rows 0..511 = sw_k_w, then sw_v_w (adjacent)
    u16* swvb  = wc + 5767168;
    u16* swob  = wc + 6029312;
    u16* l1b   = wc + 6291456;
    u16* l2b   = wc + 7340032;
    (void)swvb;

    CvtTable tab;
    const float* srcs[10] = {tgt, memory, in_proj_w, out_proj_w, sw_q_w,
                             sw_k_w, sw_v_w, sw_o_w, lin1_w, lin2_w};
    const u32 starts[10] = {0, 2097152, 4194304, 4980736, 5242880,
                            5505024, 5767168, 6029312, 6291456, 7340032};
    for (int i = 0; i < 10; ++i) { tab.src[i] = srcs[i]; tab.start[i] = starts[i]; }
    cvt_bf16_kernel<<<dim3(4096), dim3(256), 0, stream>>>(tab, wc);

    // 1. QKV projection (grid 24x64 = 1536 blocks)
    gemm64(stream, tgtb, inpb, in_proj_b, in_proj_b, 1536, qkv, NTOK, 1536, 512, 0);
    // 2. self attention (MFMA flash, 128-key chunks)
    self_attn_kernel<<<dim3(16, 32), dim3(256), 0, stream>>>(qkv, bufA);
    // 3. output projection (512 blocks)
    gemm64(stream, bufA, outpb, out_proj_b, out_proj_b, 512, bufB, NTOK, 512, 512, 0);
    // 4. x1 = LN1(bufB + tgt_bf16) -> bf16
    add_ln_kernel<<<dim3(NTOK), dim3(256), 0, stream>>>(bufB, tgtb, n1_g, n1_b, x1, 0, 0);
    // 5. sw_q projection (512 blocks)
    gemm64(stream, x1, swqb, sw_q_b, sw_q_b, 512, q2, NTOK, 512, 512, 0);
    // 6. fused sw_k + sw_v projection -> kv [4096][1024] (grid 16x64 = 1024 blocks)
    gemm64(stream, memb, swkb, sw_k_b, sw_v_b, 512, kv, NTOK, 1024, 512, 0);
    // 7. sliding-window attention (MFMA band kernel)
    sw_attn_kernel<<<dim3(16, 32), dim3(256), 0, stream>>>(q2, kv, bufA);
    // 8. sw output projection (512 blocks)
    gemm64(stream, bufA, swob, sw_o_b, sw_o_b, 512, bufB, NTOK, 512, 512, 0);
    // 9. x2 = LN2(bufB + x1) -> bf16
    add_ln_kernel<<<dim3(NTOK), dim3(256), 0, stream>>>(bufB, x1, n2_g, n2_b, x2, 0, 0);
    // 10. FFN up + ReLU (grid 32x64 = 2048 blocks)
    gemm64(stream, x2, l1b, lin1_b, lin1_b, 2048, hbuf, NTOK, 2048, 512, 1);
    // 11. FFN down (512 blocks, K=2048)
    gemm64(stream, hbuf, l2b, lin2_b, lin2_b, 512, bufA, NTOK, 512, 2048, 0);
    // 12. out = LN3(bufA + x2) -> f32 d_out
    add_ln_kernel<<<dim3(NTOK), dim3(256), 0, stream>>>(bufA, x2, n3_g, n3_b, d_out, 0, 1);
}

// Round 9
// 297.807 us; speedup vs baseline: 1.0968x; 1.0968x over previous
//
#include <hip/hip_runtime.h>

typedef unsigned short u16;
typedef unsigned int u32;

#define BATCH 4
#define NTOK 4096
#define SCALE_ATTN 0.125f

typedef float f32x4 __attribute__((ext_vector_type(4)));
typedef __bf16 bf16x8 __attribute__((ext_vector_type(8)));

__device__ __forceinline__ float b2f(u16 s) { return __uint_as_float(((u32)s) << 16); }
__device__ __forceinline__ u16 f2bf(float f) {
    u32 u = __float_as_uint(f);
    u += 0x7FFFu + ((u >> 16) & 1u);
    return (u16)(u >> 16);
}
__device__ __forceinline__ u32 pk2(float x, float y) {
    return (u32)f2bf(x) | ((u32)f2bf(y) << 16);
}
// truncating pack (attention probabilities only)
__device__ __forceinline__ u32 pk2t(float x, float y) {
    return (__float_as_uint(x) >> 16) | (__float_as_uint(y) & 0xFFFF0000u);
}
__device__ __forceinline__ uint4 pack8(float4 a, float4 b) {
    uint4 r;
    r.x = pk2(a.x, a.y); r.y = pk2(a.z, a.w);
    r.z = pk2(b.x, b.y); r.w = pk2(b.z, b.w);
    return r;
}
__device__ __forceinline__ f32x4 mfma16(uint4 a, uint4 b, f32x4 c) {
    return __builtin_amdgcn_mfma_f32_16x16x32_bf16(
        __builtin_bit_cast(bf16x8, a), __builtin_bit_cast(bf16x8, b), c, 0, 0, 0);
}

// ---------------------------------------------------------------------------
// One-shot f32 -> bf16 conversion of all weights + tgt + memory.
// ---------------------------------------------------------------------------
struct CvtTable {
    const float* src[10];
    u32 start[10];
};
__global__ __launch_bounds__(256) void cvt_bf16_kernel(CvtTable tab, u16* __restrict__ dst)
{
    u32 i8 = (blockIdx.x * 256u + threadIdx.x) * 8u;
    int t = 0;
    #pragma unroll
    for (int k = 1; k < 10; ++k) t += (i8 >= tab.start[k]) ? 1 : 0;
    const float* s = tab.src[t] + (i8 - tab.start[t]);
    float4 f0 = *(const float4*)s;
    float4 f1 = *(const float4*)(s + 4);
    *(uint4*)(dst + i8) = pack8(f0, f1);
}

// ---------------------------------------------------------------------------
// GEMM: C[M,N](bf16) = A[M,K](bf16) @ B[N,K]^T(bf16) + bias(f32), opt ReLU.
// global_load_lds(16B) staging, fragment-major LDS, double-buffered K-loop.
// 128-tile for wide GEMMs (qkv, lin1), 64-tile for N<=1024 (occupancy).
// Dual bias pointers (cols >= split use bias2) for fused concat GEMMs.
// ---------------------------------------------------------------------------
template<int BM, int BN>
__global__ __launch_bounds__(256) void gemm_lds_kernel(
    const u16* __restrict__ A, const u16* __restrict__ B,
    const float* __restrict__ bias, const float* __restrict__ bias2, int split,
    u16* __restrict__ C, int M, int N, int K, int relu)
{
    constexpr int WMF = BM / 32;
    constexpr int WNF = BN / 32;
    constexpr int AIW = BM / 32;
    constexpr int BIW = BN / 32;

    __shared__ u16 As[2][BM * 64];
    __shared__ u16 Bs[2][BN * 64];

    const int tid = threadIdx.x;
    const int wave = tid >> 6, lane = tid & 63;
    const int lm = lane & 15, quad = lane >> 4;
    const int m0 = blockIdx.y * BM, n0 = blockIdx.x * BN;
    const int wr = wave >> 1, wc = wave & 1;
    const int lk = (lane >> 4) * 8;

    f32x4 acc[WMF][WNF] = {};

    auto stage = [&](int buf, int k0) {
        #pragma unroll
        for (int t = 0; t < AIW; ++t) {
            int j = wave * AIW + t;
            int i = j >> 1, c = j & 1;
            const u16* gp = A + (size_t)(m0 + i * 16 + lm) * K + k0 + c * 32 + lk;
            __builtin_amdgcn_global_load_lds(
                (const __attribute__((address_space(1))) u32*)gp,
                (__attribute__((address_space(3))) u32*)(&As[buf][j * 512]), 16, 0, 0);
        }
        #pragma unroll
        for (int t = 0; t < BIW; ++t) {
            int j = wave * BIW + t;
            int i = j >> 1, c = j & 1;
            const u16* gp = B + (size_t)(n0 + i * 16 + lm) * K + k0 + c * 32 + lk;
            __builtin_amdgcn_global_load_lds(
                (const __attribute__((address_space(1))) u32*)gp,
                (__attribute__((address_space(3))) u32*)(&Bs[buf][j * 512]), 16, 0, 0);
        }
    };

    stage(0, 0);
    int cur = 0;
    for (int k0 = 0; k0 < K; k0 += 64) {
        __syncthreads();                    // drains loads of buf `cur`
        if (k0 + 64 < K) stage(cur ^ 1, k0 + 64);   // overlap with compute
        #pragma unroll
        for (int kk = 0; kk < 2; ++kk) {
            uint4 af[WMF], bf[WNF];
            #pragma unroll
            for (int i2 = 0; i2 < WMF; ++i2) {
                int g = wr * WMF + i2;
                af[i2] = *(const uint4*)(&As[cur][((g * 8 + kk * 4 + quad) * 16 + lm) * 8]);
            }
            #pragma unroll
            for (int j2 = 0; j2 < WNF; ++j2) {
                int g = wc * WNF + j2;
                bf[j2] = *(const uint4*)(&Bs[cur][((g * 8 + kk * 4 + quad) * 16 + lm) * 8]);
            }
            #pragma unroll
            for (int i2 = 0; i2 < WMF; ++i2)
                #pragma unroll
                for (int j2 = 0; j2 < WNF; ++j2)
                    acc[i2][j2] = mfma16(af[i2], bf[j2], acc[i2][j2]);
        }
        cur ^= 1;
    }

    #pragma unroll
    for (int j2 = 0; j2 < WNF; ++j2) {
        int cg = n0 + (wc * WNF + j2) * 16 + lm;
        float bv = (cg < split) ? bias[cg] : bias2[cg - split];
        #pragma unroll
        for (int i2 = 0; i2 < WMF; ++i2) {
            #pragma unroll
            for (int r = 0; r < 4; ++r) {
                int rg = m0 + (wr * WMF + i2) * 16 + quad * 4 + r;
                float v = acc[i2][j2][r] + bv;
                if (relu) v = fmaxf(v, 0.f);
                C[(size_t)rg * N + cg] = f2bf(v);
            }
        }
    }
}

// ---------------------------------------------------------------------------
// Fused residual add + LayerNorm over D=512.
// ---------------------------------------------------------------------------
__global__ __launch_bounds__(256) void add_ln_kernel(
    const u16* __restrict__ a, const void* __restrict__ r,
    const float* __restrict__ g, const float* __restrict__ be,
    void* __restrict__ out, int r_f32, int out_f32)
{
    const int row = blockIdx.x, tid = threadIdx.x;
    u32 av = *(const u32*)(a + (size_t)row * 512 + tid * 2);
    float r0, r1;
    if (r_f32) {
        float2 rv = *(const float2*)((const float*)r + (size_t)row * 512 + tid * 2);
        r0 = rv.x; r1 = rv.y;
    } else {
        u32 rv = *(const u32*)((const u16*)r + (size_t)row * 512 + tid * 2);
        r0 = b2f((u16)(rv & 0xFFFFu)); r1 = b2f((u16)(rv >> 16));
    }
    float v0 = b2f((u16)(av & 0xFFFFu)) + r0;
    float v1 = b2f((u16)(av >> 16)) + r1;
    float s = v0 + v1, q = v0 * v0 + v1 * v1;
    #pragma unroll
    for (int m = 1; m < 64; m <<= 1) { s += __shfl_xor(s, m); q += __shfl_xor(q, m); }
    __shared__ float ss[4], qq[4];
    int wave = tid >> 6, lane = tid & 63;
    if (lane == 0) { ss[wave] = s; qq[wave] = q; }
    __syncthreads();
    s = ss[0] + ss[1] + ss[2] + ss[3];
    q = qq[0] + qq[1] + qq[2] + qq[3];
    float mean = s * (1.f / 512.f);
    float var = q * (1.f / 512.f) - mean * mean;
    float rstd = rsqrtf(var + 1e-5f);
    float2 gv = *(const float2*)(g + tid * 2);
    float2 bv = *(const float2*)(be + tid * 2);
    float o0 = (v0 - mean) * rstd * gv.x + bv.x;
    float o1 = (v1 - mean) * rstd * gv.y + bv.y;
    if (out_f32) {
        float2 ov; ov.x = o0; ov.y = o1;
        *(float2*)((float*)out + (size_t)row * 512 + tid * 2) = ov;
    } else {
        *(u32*)((u16*)out + (size_t)row * 512 + tid * 2) = pk2(o0, o1);
    }
}

// ---------------------------------------------------------------------------
// Self-attention, full MFMA flash kernel. 64-key chunks (17 KB LDS,
// 8 blocks/CU). Round 9: XCD-aware grid — blockIdx.x = bh so all 16
// q-blocks of one (b,h) land on one XCD (linear id % 8 == bh % 8) and its
// K/V (256 KB) stays L2-resident.
// ---------------------------------------------------------------------------
__global__ __launch_bounds__(256) void self_attn_kernel(
    const u16* __restrict__ qkv, u16* __restrict__ o)
{
    const int bh = blockIdx.x;          // 0..31  (XCD = bh % 8)
    const int qb = blockIdx.y;          // 0..15
    const int b = bh >> 3, h = bh & 7;
    const int tid = threadIdx.x;
    const int lane = tid & 63, wave = tid >> 6;
    const int lm = lane & 15, quad = lane >> 4;

    __shared__ u16 Ks[64 * 64];
    __shared__ u16 Vt[64][72];

    const int qrow0 = qb * 64 + wave * 16;
    const u16* qp = qkv + ((size_t)(qrow0 + lm) * BATCH + b) * 1536 + h * 64;
    uint4 qf0 = *(const uint4*)(qp + quad * 8);
    uint4 qf1 = *(const uint4*)(qp + 32 + quad * 8);

    f32x4 o4[4] = {};
    float m_s = -1e30f, l_s = 0.f;

    for (int c0 = 0; c0 < 1024; c0 += 64) {
        #pragma unroll
        for (int t2 = 0; t2 < 2; ++t2) {
            int j = wave * 2 + t2;
            int g = j >> 1, c = j & 1;
            const u16* gp = qkv + ((size_t)(c0 + g * 16 + lm) * BATCH + b) * 1536
                            + 512 + h * 64 + c * 32 + quad * 8;
            __builtin_amdgcn_global_load_lds(
                (const __attribute__((address_space(1))) u32*)gp,
                (__attribute__((address_space(3))) u32*)(Ks + j * 512), 16, 0, 0);
        }
        #pragma unroll
        for (int i = 0; i < 2; ++i) {
            int c = tid + i * 256;
            int key = c & 63, dv = (c >> 6) * 8;
            uint4 u = *(const uint4*)(
                qkv + ((size_t)(c0 + key) * BATCH + b) * 1536 + 1024 + h * 64 + dv);
            Vt[dv + 0][key] = (u16)(u.x & 0xFFFFu);
            Vt[dv + 1][key] = (u16)(u.x >> 16);
            Vt[dv + 2][key] = (u16)(u.y & 0xFFFFu);
            Vt[dv + 3][key] = (u16)(u.y >> 16);
            Vt[dv + 4][key] = (u16)(u.z & 0xFFFFu);
            Vt[dv + 5][key] = (u16)(u.z >> 16);
            Vt[dv + 6][key] = (u16)(u.w & 0xFFFFu);
            Vt[dv + 7][key] = (u16)(u.w >> 16);
        }
        __syncthreads();

        f32x4 s[4] = {};
        #pragma unroll
        for (int t = 0; t < 4; ++t) {
            uint4 k0 = *(const uint4*)(Ks + t * 1024 + quad * 128 + lm * 8);
            uint4 k1 = *(const uint4*)(Ks + t * 1024 + 512 + quad * 128 + lm * 8);
            s[t] = mfma16(k0, qf0, s[t]);
            s[t] = mfma16(k1, qf1, s[t]);
        }

        float mx = -1e30f;
        #pragma unroll
        for (int t = 0; t < 4; ++t)
            #pragma unroll
            for (int r = 0; r < 4; ++r) {
                s[t][r] *= SCALE_ATTN;
                mx = fmaxf(mx, s[t][r]);
            }
        mx = fmaxf(mx, __shfl_xor(mx, 16));
        mx = fmaxf(mx, __shfl_xor(mx, 32));
        float mn = fmaxf(m_s, mx);
        float alpha = __expf(m_s - mn);
        m_s = mn;
        float ps = 0.f;
        u32 pkx[4], pky[4];
        #pragma unroll
        for (int t = 0; t < 4; ++t) {
            float p0 = __expf(s[t][0] - mn);
            float p1 = __expf(s[t][1] - mn);
            float p2 = __expf(s[t][2] - mn);
            float p3 = __expf(s[t][3] - mn);
            ps += (p0 + p1) + (p2 + p3);
            pkx[t] = pk2t(p0, p1);
            pky[t] = pk2t(p2, p3);
        }
        ps += __shfl_xor(ps, 16);
        ps += __shfl_xor(ps, 32);
        l_s = l_s * alpha + ps;
        float av[4];
        #pragma unroll
        for (int r = 0; r < 4; ++r) av[r] = __shfl(alpha, quad * 20 + r);
        #pragma unroll
        for (int t = 0; t < 4; ++t)
            #pragma unroll
            for (int r = 0; r < 4; ++r) o4[t][r] *= av[r];

        #pragma unroll
        for (int kh = 0; kh < 2; ++kh) {
            int src1 = lm + 32 * (quad & 1);
            int src2 = src1 + 16;
            u32 xA = (u32)__shfl((int)pkx[2 * kh], src1);
            u32 xB = (u32)__shfl((int)pkx[2 * kh + 1], src1);
            u32 yA = (u32)__shfl((int)pky[2 * kh], src1);
            u32 yB = (u32)__shfl((int)pky[2 * kh + 1], src1);
            u32 zA = (u32)__shfl((int)pkx[2 * kh], src2);
            u32 zB = (u32)__shfl((int)pkx[2 * kh + 1], src2);
            u32 wA = (u32)__shfl((int)pky[2 * kh], src2);
            u32 wB = (u32)__shfl((int)pky[2 * kh + 1], src2);
            bool hiq = quad >= 2;
            uint4 pf;
            pf.x = hiq ? xB : xA;
            pf.y = hiq ? yB : yA;
            pf.z = hiq ? zB : zA;
            pf.w = hiq ? wB : wA;
            #pragma unroll
            for (int t = 0; t < 4; ++t) {
                uint4 vf = *(const uint4*)(&Vt[t * 16 + lm][kh * 32 + quad * 8]);
                o4[t] = mfma16(pf, vf, o4[t]);
            }
        }
        __syncthreads();
    }

    float linv = 1.f / l_s;
    float lv[4];
    #pragma unroll
    for (int r = 0; r < 4; ++r) lv[r] = __shfl(linv, quad * 20 + r);
    #pragma unroll
    for (int t = 0; t < 4; ++t) {
        #pragma unroll
        for (int r = 0; r < 4; ++r) {
            int row = qrow0 + quad * 4 + r;
            o[((size_t)row * BATCH + b) * 512 + h * 64 + t * 16 + lm] =
                f2bf(o4[t][r] * lv[r]);
        }
    }
}

// ---------------------------------------------------------------------------
// Sliding-window cross attention, MFMA band kernel (fused kv input).
// Round 9: XCD-aware grid (blockIdx.x = bh).
// ---------------------------------------------------------------------------
__global__ __launch_bounds__(256) void sw_attn_kernel(
    const u16* __restrict__ q2, const u16* __restrict__ kv, u16* __restrict__ o)
{
    const int bh = blockIdx.x;          // 0..31  (XCD = bh % 8)
    const int qb = blockIdx.y;          // 0..15
    const int b = bh >> 3, h = bh & 7;
    const int tid = threadIdx.x;
    const int lane = tid & 63, wave = tid >> 6;
    const int lm = lane & 15, quad = lane >> 4;

    __shared__ u16 Ks[14 * 512];
    __shared__ u16 Vt[64][120];

    const int kbase = qb * 64 - 16;
    const int qrow0 = qb * 64 + wave * 16;

    const u16* qp = q2 + ((size_t)(qrow0 + lm) * BATCH + b) * 512 + h * 64;
    uint4 qf0 = *(const uint4*)(qp + quad * 8);
    uint4 qf1 = *(const uint4*)(qp + 32 + quad * 8);

    #pragma unroll
    for (int t2 = 0; t2 < 4; ++t2) {
        int j = wave * 4 + t2;
        if (j < 14) {
            int g = j >> 1, c = j & 1;
            int key = kbase + g * 16 + lm;
            key = min(max(key, 0), 1023);
            const u16* gp = kv + ((size_t)key * BATCH + b) * 1024 + h * 64
                            + c * 32 + quad * 8;
            __builtin_amdgcn_global_load_lds(
                (const __attribute__((address_space(1))) u32*)gp,
                (__attribute__((address_space(3))) u32*)(Ks + j * 512), 16, 0, 0);
        }
    }
    #pragma unroll
    for (int i = 0; i < 4; ++i) {
        int c = tid + i * 256;
        if (c < 896) {
            int key = c >> 3, dv = (c & 7) * 8;
            int j = kbase + key;
            j = min(max(j, 0), 1023);
            uint4 u = *(const uint4*)(kv + ((size_t)j * BATCH + b) * 1024 + 512 + h * 64 + dv);
            Vt[dv + 0][key] = (u16)(u.x & 0xFFFFu);
            Vt[dv + 1][key] = (u16)(u.x >> 16);
            Vt[dv + 2][key] = (u16)(u.y & 0xFFFFu);
            Vt[dv + 3][key] = (u16)(u.y >> 16);
            Vt[dv + 4][key] = (u16)(u.z & 0xFFFFu);
            Vt[dv + 5][key] = (u16)(u.z >> 16);
            Vt[dv + 6][key] = (u16)(u.w & 0xFFFFu);
            Vt[dv + 7][key] = (u16)(u.w >> 16);
        }
    }
    __syncthreads();

    f32x4 s[4] = {};
    #pragma unroll
    for (int t = 0; t < 4; ++t) {
        int tw = wave + t;
        uint4 k0 = *(const uint4*)(Ks + (tw * 2 + 0) * 512 + quad * 128 + lm * 8);
        uint4 k1 = *(const uint4*)(Ks + (tw * 2 + 1) * 512 + quad * 128 + lm * 8);
        s[t] = mfma16(k0, qf0, s[t]);
        s[t] = mfma16(k1, qf1, s[t]);
    }

    float mx = -1e30f;
    #pragma unroll
    for (int t = 0; t < 4; ++t) {
        #pragma unroll
        for (int r = 0; r < 4; ++r) {
            int kl = t * 16 + quad * 4 + r;
            int jj = qrow0 - 16 + kl;
            int d = kl - lm;
            bool valid = (d >= 0) && (d <= 32) && (jj >= 0) && (jj < 1024);
            s[t][r] = valid ? s[t][r] * SCALE_ATTN : -1e30f;
            mx = fmaxf(mx, s[t][r]);
        }
    }
    mx = fmaxf(mx, __shfl_xor(mx, 16));
    mx = fmaxf(mx, __shfl_xor(mx, 32));
    float ps = 0.f;
    u32 pkx[4], pky[4];
    #pragma unroll
    for (int t = 0; t < 4; ++t) {
        float p0 = __expf(s[t][0] - mx);
        float p1 = __expf(s[t][1] - mx);
        float p2 = __expf(s[t][2] - mx);
        float p3 = __expf(s[t][3] - mx);
        ps += (p0 + p1) + (p2 + p3);
        pkx[t] = pk2t(p0, p1);
        pky[t] = pk2t(p2, p3);
    }
    ps += __shfl_xor(ps, 16);
    ps += __shfl_xor(ps, 32);

    f32x4 o4[4] = {};
    #pragma unroll
    for (int kh = 0; kh < 2; ++kh) {
        int src1 = lm + 32 * (quad & 1);
        int src2 = src1 + 16;
        u32 xA = (u32)__shfl((int)pkx[2 * kh], src1);
        u32 xB = (u32)__shfl((int)pkx[2 * kh + 1], src1);
        u32 yA = (u32)__shfl((int)pky[2 * kh], src1);
        u32 yB = (u32)__shfl((int)pky[2 * kh + 1], src1);
        u32 zA = (u32)__shfl((int)pkx[2 * kh], src2);
        u32 zB = (u32)__shfl((int)pkx[2 * kh + 1], src2);
        u32 wA = (u32)__shfl((int)pky[2 * kh], src2);
        u32 wB = (u32)__shfl((int)pky[2 * kh + 1], src2);
        bool hiq = quad >= 2;
        uint4 pf;
        pf.x = hiq ? xB : xA;
        pf.y = hiq ? yB : yA;
        pf.z = hiq ? zB : zA;
        pf.w = hiq ? wB : wA;
        #pragma unroll
        for (int t = 0; t < 4; ++t) {
            uint4 vf = *(const uint4*)(&Vt[t * 16 + lm][wave * 16 + kh * 32 + quad * 8]);
            o4[t] = mfma16(pf, vf, o4[t]);
        }
    }

    float linv = 1.f / ps;
    float lv[4];
    #pragma unroll
    for (int r = 0; r < 4; ++r) lv[r] = __shfl(linv, quad * 20 + r);
    #pragma unroll
    for (int t = 0; t < 4; ++t) {
        #pragma unroll
        for (int r = 0; r < 4; ++r) {
            int row = qrow0 + quad * 4 + r;
            o[((size_t)row * BATCH + b) * 512 + h * 64 + t * 16 + lm] =
                f2bf(o4[t][r] * lv[r]);
        }
    }
}

// ---------------------------------------------------------------------------
// Host orchestration
// ---------------------------------------------------------------------------
static inline void gemm128(hipStream_t st, const u16* A, const u16* B,
                           const float* bias, const float* bias2, int split,
                           u16* C, int M, int N, int K, int relu)
{
    dim3 g(N / 128, M / 128);
    gemm_lds_kernel<128, 128><<<g, dim3(256), 0, st>>>(A, B, bias, bias2, split,
                                                       C, M, N, K, relu);
}
static inline void gemm64(hipStream_t st, const u16* A, const u16* B,
                          const float* bias, const float* bias2, int split,
                          u16* C, int M, int N, int K, int relu)
{
    dim3 g(N / 64, M / 64);
    gemm_lds_kernel<64, 64><<<g, dim3(256), 0, st>>>(A, B, bias, bias2, split,
                                                     C, M, N, K, relu);
}

extern "C" void kernel_launch(void* const* d_in, const int* in_sizes, int n_in,
                              void* d_out, int out_size, void* d_ws, size_t ws_size,
                              hipStream_t stream)
{
    const float* tgt        = (const float*)d_in[0];
    const float* memory     = (const float*)d_in[1];
    const float* in_proj_w  = (const float*)d_in[2];
    const float* in_proj_b  = (const float*)d_in[3];
    const float* out_proj_w = (const float*)d_in[4];
    const float* out_proj_b = (const float*)d_in[5];
    const float* sw_q_w = (const float*)d_in[6];
    const float* sw_q_b = (const float*)d_in[7];
    const float* sw_k_w = (const float*)d_in[8];
    const float* sw_k_b = (const float*)d_in[9];
    const float* sw_v_w = (const float*)d_in[10];
    const float* sw_v_b = (const float*)d_in[11];
    const float* sw_o_w = (const float*)d_in[12];
    const float* sw_o_b = (const float*)d_in[13];
    const float* lin1_w = (const float*)d_in[14];
    const float* lin1_b = (const float*)d_in[15];
    const float* lin2_w = (const float*)d_in[16];
    const float* lin2_b = (const float*)d_in[17];
    const float* n1_g = (const float*)d_in[18];
    const float* n1_b = (const float*)d_in[19];
    const float* n2_g = (const float*)d_in[20];
    const float* n2_b = (const float*)d_in[21];
    const float* n3_g = (const float*)d_in[22];
    const float* n3_b = (const float*)d_in[23];

    u16* ws = (u16*)d_ws;
    u16* qkv  = ws;                    // 6291456
    u16* x1   = ws + 6291456;          // 2097152
    u16* bufA = ws + 8388608;          // 2097152
    u16* bufB = ws + 10485760;         // 2097152
    u16* x2   = ws + 12582912;         // 2097152
    u16* q2 = qkv;                     // 2097152 (reuse qkv region)
    u16* kv = qkv + 2097152;           // 4194304 = [4096][1024] fused k|v
    u16* hbuf = qkv;                   // spans qkv+x1 (both dead by FFN)

    u16* wc = ws + 14680064;
    u16* tgtb  = wc;
    u16* memb  = wc + 2097152;
    u16* inpb  = wc + 4194304;
    u16* outpb = wc + 4980736;
    u16* swqb  = wc + 5242880;
    u16* swkb  = wc + 5505024;         // rows 0..511 = sw_k_w, then sw_v_w (adjacent)
    u16* swvb  = wc + 5767168;
    u16* swob  = wc + 6029312;
    u16* l1b   = wc + 6291456;
    u16* l2b   = wc + 7340032;
    (void)swvb;

    CvtTable tab;
    const float* srcs[10] = {tgt, memory, in_proj_w, out_proj_w, sw_q_w,
                             sw_k_w, sw_v_w, sw_o_w, lin1_w, lin2_w};
    const u32 starts[10] = {0, 2097152, 4194304, 4980736, 5242880,
                            5505024, 5767168, 6029312, 6291456, 7340032};
    for (int i = 0; i < 10; ++i) { tab.src[i] = srcs[i]; tab.start[i] = starts[i]; }
    cvt_bf16_kernel<<<dim3(4096), dim3(256), 0, stream>>>(tab, wc);

    // 1. QKV projection (128-tile, grid 12x32 = 384 blocks)
    gemm128(stream, tgtb, inpb, in_proj_b, in_proj_b, 1536, qkv, NTOK, 1536, 512, 0);
    // 2. self attention (MFMA flash, XCD-swizzled grid)
    self_attn_kernel<<<dim3(32, 16), dim3(256), 0, stream>>>(qkv, bufA);
    // 3. output projection (64-tile, 512 blocks)
    gemm64(stream, bufA, outpb, out_proj_b, out_proj_b, 512, bufB, NTOK, 512, 512, 0);
    // 4. x1 = LN1(bufB + tgt_bf16) -> bf16
    add_ln_kernel<<<dim3(NTOK), dim3(256), 0, stream>>>(bufB, tgtb, n1_g, n1_b, x1, 0, 0);
    // 5. sw_q projection (64-tile, 512 blocks)
    gemm64(stream, x1, swqb, sw_q_b, sw_q_b, 512, q2, NTOK, 512, 512, 0);
    // 6. fused sw_k + sw_v projection -> kv (64-tile, 1024 blocks)
    gemm64(stream, memb, swkb, sw_k_b, sw_v_b, 512, kv, NTOK, 1024, 512, 0);
    // 7. sliding-window attention (MFMA band, XCD-swizzled grid)
    sw_attn_kernel<<<dim3(32, 16), dim3(256), 0, stream>>>(q2, kv, bufA);
    // 8. sw output projection (64-tile, 512 blocks)
    gemm64(stream, bufA, swob, sw_o_b, sw_o_b, 512, bufB, NTOK, 512, 512, 0);
    // 9. x2 = LN2(bufB + x1) -> bf16
    add_ln_kernel<<<dim3(NTOK), dim3(256), 0, stream>>>(bufB, x1, n2_g, n2_b, x2, 0, 0);
    // 10. FFN up + ReLU (128-tile, grid 16x32 = 512 blocks)
    gemm128(stream, x2, l1b, lin1_b, lin1_b, 2048, hbuf, NTOK, 2048, 512, 1);
    // 11. FFN down (64-tile, 512 blocks, K=2048)
    gemm64(stream, hbuf, l2b, lin2_b, lin2_b, 512, bufA, NTOK, 512, 2048, 0);
    // 12. out = LN3(bufA + x2) -> f32 d_out
    add_ln_kernel<<<dim3(NTOK), dim3(256), 0, stream>>>(bufA, x2, n3_g, n3_b, d_out, 0, 1);
}